// Round 18
// baseline (145.544 us; speedup 1.0000x reference)
//
#include <hip/hip_runtime.h>

// Gaussian VQ forward. R17 core (validated 60.8us, absmax 3.23) with:
//  - vq_finalize FUSED into vq_main (last-block pattern, device atomics)
//  - ws zeroing folded into vq_prep (memsetAsync dispatch removed)
//  - cnorm staged to LDS once (K-loop global loads -> ds_reads)
// Scoring/merge/exact-top-2-rescore BYTE-IDENTICAL to R17 (frozen invariant).
// bs=64, dim_z=64, W=H=32 -> N=65536 rows, K=1024 codes, D=64.
//
// ws layout (bytes):
//   [0    ..  511] : 64 (kld_discrete, kld_continuous) partial pairs (float)
//   [512  .. 4607] : cnorm[1024] fp32 (exact)
//   [4608 .. 8703] : counts[1024] uint
//   [8704 .. 8707] : done-counter (uint)
//   [8768 ..     ] : cb_hi bf16[1024][64]  (131072 B)
#define WS_CNORM_B  512
#define WS_COUNTS_B 4608
#define WS_CTR_B    8704
#define WS_CBHI_B   8768

typedef __attribute__((ext_vector_type(8))) short short8;
typedef __attribute__((ext_vector_type(4))) float f32x4;

__device__ __forceinline__ unsigned short f2bf(float x) {
  unsigned u = __builtin_bit_cast(unsigned, x);
  u += 0x7fffu + ((u >> 16) & 1u);
  return (unsigned short)(u >> 16);
}
__device__ __forceinline__ int qw(int r, int d) {
  return (r << 6) | (d ^ (r & 31));
}

// ---- prep: zero stats regions + codebook -> bf16 + exact ||c||^2 ----
__global__ __launch_bounds__(256) void vq_prep(const float* __restrict__ cb,
                                               char* __restrict__ ws) {
  int tid = blockIdx.x * 256 + threadIdx.x;
  // fold the old memsetAsync: loss pairs [0,512), counts+ctr [4608,8708)
  unsigned* w32 = (unsigned*)ws;
  if (tid < 128) w32[tid] = 0u;                    // loss slots
  if (tid < 1025) w32[1152 + tid] = 0u;            // counts + done-counter
  int k = tid >> 6;
  float v = cb[tid];
  ((unsigned short*)(ws + WS_CBHI_B))[tid] = f2bf(v);
  float s = v * v;
  #pragma unroll
  for (int o = 32; o > 0; o >>= 1) s += __shfl_down(s, o);
  if ((threadIdx.x & 63) == 0) ((float*)(ws + WS_CNORM_B))[k] = s;
}

// LDS (bytes):
//   [0, 16384)      chunk dbuf: parity p at [p*8192, +8192) (64 codes bf16,
//                   swizzled). Prologue: z bf16 staging at [0, 8192).
//                   Epilogue: fp32 gather buffer [0, 16384).
//   [16384, 17664)  row state: 64 x {m, S1, S2, b1, b2} (20 B, scalar stores)
//                   (reused as finalize reduce buffer at the very end)
//   [17664, 17920)  fidx[64] (reused as last-block flag after gather)
//   [17920, 22016)  cn2l[1024] = -w * cnorm[k]
#define ST_OFF   16384
#define FIDX_OFF 17664
#define CN2L_OFF 17920

__global__ __launch_bounds__(256, 4) void vq_main(const float* __restrict__ z,
                                                  const float* __restrict__ cb,
                                                  const float* __restrict__ var_q,
                                                  char* __restrict__ ws,
                                                  float* __restrict__ out) {
  __shared__ __align__(16) char smem[22016];

  const int t = threadIdx.x;
  const int b = blockIdx.x;          // 1024 blocks, 64 rows each
  const int bb = b >> 4, p0 = (b & 15) << 6;
  const int l = t & 63, wv = t >> 6;           // 4 waves
  const int lg = l >> 4, lr = l & 15;
  const float w = 0.5f / fmaxf(var_q[0], 1e-10f);
  const float w2 = 2.f * w;
  const float nw = -w;

  // ---- stage z (64 rows) -> bf16 at [0,8192), swizzled [p][d];
  //      stage cn2l = -w*cnorm into LDS ----
  for (int i = 0; i < 8; ++i) {
    int idx = t + i * 256;             // 2048 u32 slots: p(64) x d2(32)
    int d2 = idx >> 6, p = idx & 63;
    float v0 = z[bb * 65536 + (2 * d2) * 1024 + p0 + p];
    float v1 = z[bb * 65536 + (2 * d2 + 1) * 1024 + p0 + p];
    unsigned short h0 = f2bf(v0), h1 = f2bf(v1);
    int byte = (p * 128 + d2 * 4) ^ ((p & 7) << 4);
    *(unsigned*)(smem + byte) = ((unsigned)h1 << 16) | h0;
  }
  {
    const float* cnorm = (const float*)(ws + WS_CNORM_B);
    float* cn2l = (float*)(smem + CN2L_OFF);
    #pragma unroll
    for (int i = 0; i < 4; ++i) cn2l[t + i * 256] = nw * cnorm[t + i * 256];
  }
  __syncthreads();

  // ---- A fragments: wave's 16 rows (row = wv*16 + lr) ----
  short8 a_hi[2];
  {
    int row = wv * 16 + lr;
    #pragma unroll
    for (int ks = 0; ks < 2; ++ks) {
      int byte = (row * 128 + ks * 64 + lg * 16) ^ ((row & 7) << 4);
      a_hi[ks] = *(const short8*)(smem + byte);
    }
  }
  __syncthreads();  // z reads done; region becomes chunk dbuf

  // ---- prologue: stage chunk 0 (64 codes bf16 = 8KB) into parity 0 ----
  const char* cbh = ws + WS_CBHI_B;
  {
    #pragma unroll
    for (int pas = 0; pas < 2; ++pas) {
      int o = t + pas * 256;           // o in [0,512): 16B units
      int dst = (o * 16) ^ (((o >> 3) & 7) << 4);
      *(f32x4*)(smem + dst) = *(const f32x4*)(cbh + o * 16);
    }
  }
  __syncthreads();

  // per-lane state: 4 rows (row = wv*16 + lg*4 + j).
  // b1/b2 PACKED (validated R10/R11/R13/R17): low 10 mantissa bits cleared,
  // code OR'd in; exact fp32 rescore of BOTH candidates arbitrates.
  float m[4], S1[4], S2[4], b1[4], b2[4];
  #pragma unroll
  for (int j = 0; j < 4; ++j) {
    m[j] = -1e30f; S1[j] = 0.f; S2[j] = 0.f; b1[j] = -1e30f; b2[j] = -1e30f;
  }

  const float* cn2l = (const float*)(smem + CN2L_OFF);

  for (int ch = 0; ch < 16; ++ch) {
    char* cur = smem + (ch & 1) * 8192;
    char* nxt = smem + ((ch + 1) & 1) * 8192;
    f32x4 rh0, rh1;
    const bool pf = ch < 15;
    if (pf) {  // prefetch next chunk into regs; latency hides under compute
      const char* sh = cbh + (ch + 1) * 8192 + t * 16;
      rh0 = *(const f32x4*)sh;
      rh1 = *(const f32x4*)(sh + 4096);
    }
    float cn2[4];
    #pragma unroll
    for (int ct = 0; ct < 4; ++ct) cn2[ct] = cn2l[ch * 64 + ct * 16 + lr];

    f32x4 acc[4];
    #pragma unroll
    for (int ct = 0; ct < 4; ++ct) {
      f32x4 a = {};
      #pragma unroll
      for (int ks = 0; ks < 2; ++ks) {
        int cr = ct * 16 + lr;
        int byte = (cr * 128 + ks * 64 + lg * 16) ^ ((cr & 7) << 4);
        short8 bh = *(const short8*)(cur + byte);
        a = __builtin_amdgcn_mfma_f32_16x16x32_bf16(a_hi[ks], bh, a, 0, 0, 0);
      }
      acc[ct] = a;
    }

    // epilogue: online-max rescale + packed fmax top-2 (VERBATIM R17)
    #pragma unroll
    for (int j = 0; j < 4; ++j) {
      float lv[4];
      #pragma unroll
      for (int ct = 0; ct < 4; ++ct) lv[ct] = fmaf(acc[ct][j], w2, cn2[ct]);
      float lm = fmaxf(fmaxf(lv[0], lv[1]), fmaxf(lv[2], lv[3]));
      float mn = fmaxf(m[j], lm);
      float sc = __expf(m[j] - mn);
      S1[j] *= sc; S2[j] *= sc; m[j] = mn;
      #pragma unroll
      for (int ct = 0; ct < 4; ++ct) {
        float x = lv[ct];
        unsigned ku = (unsigned)(ch * 64 + ct * 16 + lr);
        unsigned xb = (__builtin_bit_cast(unsigned, x) & ~1023u) | ku;
        float xp = __builtin_bit_cast(float, xb);
        float tm = fminf(b1[j], xp);
        b1[j] = fmaxf(b1[j], xp);
        b2[j] = fmaxf(b2[j], tm);
        float e = __expf(x - mn);
        S1[j] += e;
        S2[j] = fmaf(x, e, S2[j]);   // S2 = sum x * e^{x-m}
      }
    }

    if (pf) {
      #pragma unroll
      for (int pas = 0; pas < 2; ++pas) {
        int o = t + pas * 256;
        int dst = (o * 16) ^ (((o >> 3) & 7) << 4);
        *(f32x4*)(nxt + dst) = pas ? rh1 : rh0;
      }
    }
    __syncthreads();
  }

  // ---- merge the 16 code-columns within each wave (VERBATIM R17) ----
  #pragma unroll
  for (int st = 1; st < 16; st <<= 1) {
    #pragma unroll
    for (int j = 0; j < 4; ++j) {
      float om = __shfl_xor(m[j], st);
      float o1 = __shfl_xor(S1[j], st);
      float o2 = __shfl_xor(S2[j], st);
      float ov1 = __shfl_xor(b1[j], st);
      float ov2 = __shfl_xor(b2[j], st);
      float mn = fmaxf(m[j], om);
      float sa = __expf(m[j] - mn), sb = __expf(om - mn);
      S1[j] = sa * S1[j] + sb * o1;
      S2[j] = sa * S2[j] + sb * o2;
      m[j] = mn;
      float nb1 = fmaxf(b1[j], ov1);
      float nb2 = fmaxf(fminf(b1[j], ov1), fmaxf(b2[j], ov2));
      b1[j] = nb1; b2[j] = nb2;
    }
  }

  // ---- state write: 64 rows x 20 B scalar stores (VERBATIM R17) ----
  float* stw = (float*)(smem + ST_OFF);
  if (lr == 0) {
    #pragma unroll
    for (int j = 0; j < 4; ++j) {
      int r = wv * 16 + lg * 4 + j;
      float* p = stw + r * 5;
      p[0] = m[j]; p[1] = S1[j]; p[2] = S2[j]; p[3] = b1[j]; p[4] = b2[j];
    }
  }
  __syncthreads();

  // ---- per-row tail (wave 0): entropy + exact fp32 top-2 rescore ----
  int* fidx = (int*)(smem + FIDX_OFF);
  const float* cnf = (const float*)(ws + WS_CNORM_B);
  float rowent = 0.f, d2min = 0.f;
  if (t < 64) {
    const float* p = stw + t * 5;
    float mn = p[0], s1 = p[1], s2 = p[2];
    int ka = (int)(__builtin_bit_cast(unsigned, p[3]) & 1023u);
    int kb = (int)(__builtin_bit_cast(unsigned, p[4]) & 1023u);
    rowent = (s2 - mn * s1) / s1 - __logf(s1);
    const float* zp = z + bb * 65536 + p0 + t;
    const float* c1p = cb + ka * 64;
    const float* c2p = cb + kb * 64;
    float zn = 0.f, d1 = 0.f, d2 = 0.f;
    #pragma unroll 4
    for (int d4 = 0; d4 < 16; ++d4) {
      f32x4 ca = *(const f32x4*)(c1p + d4 * 4);
      f32x4 cc = *(const f32x4*)(c2p + d4 * 4);
      #pragma unroll
      for (int e = 0; e < 4; ++e) {
        float v = zp[(d4 * 4 + e) * 1024];
        zn = fmaf(v, v, zn);
        d1 = fmaf(v, ca[e], d1);
        d2 = fmaf(v, cc[e], d2);
      }
    }
    float da = zn + cnf[ka] - 2.f * d1;
    float db = zn + cnf[kb] - 2.f * d2;
    int kwin; float dwin;
    if (da < db || (da == db && ka < kb)) { kwin = ka; dwin = da; }
    else { kwin = kb; dwin = db; }
    fidx[t] = kwin;
    d2min = dwin;
    atomicAdd((unsigned*)(ws + WS_COUNTS_B) + kwin, 1u);
  }
  #pragma unroll
  for (int o = 32; o > 0; o >>= 1) {
    rowent += __shfl_down(rowent, o);
    d2min += __shfl_down(d2min, o);
  }
  if (t == 0) {
    float* wsf = (float*)ws;
    int slot = b & 63;
    atomicAdd(&wsf[slot * 2], rowent);
    atomicAdd(&wsf[slot * 2 + 1], d2min);
  }
  __syncthreads();

  // ---- gather chosen codes via LDS (fp32), write transposed coalesced ----
  float* zl = (float*)smem;  // dbuf region dead now (4096 words used)
  for (int i = 0; i < 16; ++i) {
    int idx = t + i * 256;
    int r = idx >> 6, d = idx & 63;
    zl[qw(r, d)] = cb[fidx[r] * 64 + d];
  }
  __syncthreads();
  float* outz = out + bb * 65536 + p0;
  #pragma unroll
  for (int i = 0; i < 4; ++i) {
    int q = t + i * 256;
    int d = q >> 4, rq = q & 15, r = rq << 2;
    f32x4 v;
    v.x = zl[qw(r + 0, d)];
    v.y = zl[qw(r + 1, d)];
    v.z = zl[qw(r + 2, d)];
    v.w = zl[qw(r + 3, d)];
    *(f32x4*)&outz[d * 1024 + r] = v;
  }

  // ---- fused finalize: last block assembles loss + perplexity ----
  __syncthreads();                 // fidx reads done; reuse as flag
  __threadfence();                 // this block's atomics visible device-wide
  unsigned* flag = (unsigned*)(smem + FIDX_OFF);
  if (t == 0) {
    unsigned done = atomicAdd((unsigned*)(ws + WS_CTR_B), 1u);
    *flag = (done == 1023u) ? 1u : 0u;
  }
  __syncthreads();
  if (*flag) {
    const unsigned* counts = (const unsigned*)(ws + WS_COUNTS_B);
    const float* wsf = (const float*)ws;
    float term = 0.f, pd = 0.f, pc = 0.f;
    #pragma unroll
    for (int i = 0; i < 4; ++i) {
      float avg = (float)counts[t + i * 256] * (1.0f / 65536.0f);
      term += avg * __logf(avg + 1e-7f);
    }
    if (t < 64) { pd = wsf[2 * t]; pc = wsf[2 * t + 1]; }
    #pragma unroll
    for (int o = 32; o > 0; o >>= 1) {
      term += __shfl_down(term, o);
      pd += __shfl_down(pd, o);
      pc += __shfl_down(pc, o);
    }
    float* red = (float*)(smem + ST_OFF);
    if (l == 0) { red[wv * 3] = term; red[wv * 3 + 1] = pd; red[wv * 3 + 2] = pc; }
    __syncthreads();
    if (t == 0) {
      float ts = 0.f, ps = 0.f, cs = 0.f;
      #pragma unroll
      for (int i = 0; i < 4; ++i) {
        ts += red[i * 3]; ps += red[i * 3 + 1]; cs += red[i * 3 + 2];
      }
      out[4194304] = ps / 64.f + w * cs / 64.f;
      out[4194305] = __expf(-ts);
    }
  }
}

extern "C" void kernel_launch(void* const* d_in, const int* in_sizes, int n_in,
                              void* d_out, int out_size, void* d_ws, size_t ws_size,
                              hipStream_t stream) {
  const float* z = (const float*)d_in[0];
  const float* vq = (const float*)d_in[1];
  const float* cb = (const float*)d_in[2];
  float* out = (float*)d_out;
  char* ws = (char*)d_ws;

  vq_prep<<<256, 256, 0, stream>>>(cb, ws);
  vq_main<<<1024, 256, 0, stream>>>(z, cb, vq, ws, out);
}

// Round 19
// 58.122 us; speedup vs baseline: 2.5041x; 2.5041x over previous
//
#include <hip/hip_runtime.h>

// Gaussian VQ forward. FULL REVERT to R17 (validated 60.8us, absmax 3.23):
// separate prep/main/finalize kernels, NO device fences, no cn2l staging.
// Only R18 piece kept: ws zeroing folded into vq_prep (dispatch saved;
// proven correct by R18's pass). R18's fused-finalize __threadfence was a
// 2.4x uniform slowdown (XCD coherence tax) — banned.
// bs=64, dim_z=64, W=H=32 -> N=65536 rows, K=1024 codes, D=64.
//
// ws layout (bytes):
//   [0    ..  511] : 64 (kld_discrete, kld_continuous) partial pairs (float)
//   [512  .. 4607] : cnorm[1024] fp32 (exact)
//   [4608 .. 8703] : counts[1024] uint
//   [8704 ..     ] : cb_hi bf16[1024][64]  (131072 B)
#define WS_CNORM_B  512
#define WS_COUNTS_B 4608
#define WS_CBHI_B   8704

typedef __attribute__((ext_vector_type(8))) short short8;
typedef __attribute__((ext_vector_type(4))) float f32x4;

__device__ __forceinline__ unsigned short f2bf(float x) {
  unsigned u = __builtin_bit_cast(unsigned, x);
  u += 0x7fffu + ((u >> 16) & 1u);
  return (unsigned short)(u >> 16);
}
__device__ __forceinline__ int qw(int r, int d) {
  return (r << 6) | (d ^ (r & 31));
}

// ---- prep: zero stats + codebook -> bf16 + exact ||c||^2 ----
__global__ __launch_bounds__(256) void vq_prep(const float* __restrict__ cb,
                                               char* __restrict__ ws) {
  int tid = blockIdx.x * 256 + threadIdx.x;
  unsigned* w32 = (unsigned*)ws;
  if (tid < 128) w32[tid] = 0u;                    // loss partial pairs
  if (tid < 1024) w32[1152 + tid] = 0u;            // counts
  int k = tid >> 6;
  float v = cb[tid];
  ((unsigned short*)(ws + WS_CBHI_B))[tid] = f2bf(v);
  float s = v * v;
  #pragma unroll
  for (int o = 32; o > 0; o >>= 1) s += __shfl_down(s, o);
  if ((threadIdx.x & 63) == 0) ((float*)(ws + WS_CNORM_B))[k] = s;
}

// LDS (bytes) — verbatim R17:
//   [0, 16384)      chunk dbuf: parity p at [p*8192, +8192) (64 codes bf16,
//                   swizzled). Prologue: z bf16 staging at [0, 8192).
//                   Epilogue: fp32 gather buffer [0, 16384).
//   [16384, 17664)  row state: 64 x {m, S1, S2, b1, b2} (20 B, scalar stores)
//   [17664, 17920)  fidx[64]
#define ST_OFF   16384
#define FIDX_OFF 17664

__global__ __launch_bounds__(256, 4) void vq_main(const float* __restrict__ z,
                                                  const float* __restrict__ cb,
                                                  const float* __restrict__ var_q,
                                                  char* __restrict__ ws,
                                                  float* __restrict__ out) {
  __shared__ __align__(16) char smem[17920];

  const int t = threadIdx.x;
  const int b = blockIdx.x;          // 1024 blocks, 64 rows each
  const int bb = b >> 4, p0 = (b & 15) << 6;
  const int l = t & 63, wv = t >> 6;           // 4 waves
  const int lg = l >> 4, lr = l & 15;
  const float w = 0.5f / fmaxf(var_q[0], 1e-10f);
  const float w2 = 2.f * w;
  const float nw = -w;

  // ---- stage z (64 rows) -> bf16 at [0,8192), swizzled [p][d] ----
  for (int i = 0; i < 8; ++i) {
    int idx = t + i * 256;             // 2048 u32 slots: p(64) x d2(32)
    int d2 = idx >> 6, p = idx & 63;
    float v0 = z[bb * 65536 + (2 * d2) * 1024 + p0 + p];
    float v1 = z[bb * 65536 + (2 * d2 + 1) * 1024 + p0 + p];
    unsigned short h0 = f2bf(v0), h1 = f2bf(v1);
    int byte = (p * 128 + d2 * 4) ^ ((p & 7) << 4);
    *(unsigned*)(smem + byte) = ((unsigned)h1 << 16) | h0;
  }
  __syncthreads();

  // ---- A fragments: wave's 16 rows (row = wv*16 + lr) ----
  short8 a_hi[2];
  {
    int row = wv * 16 + lr;
    #pragma unroll
    for (int ks = 0; ks < 2; ++ks) {
      int byte = (row * 128 + ks * 64 + lg * 16) ^ ((row & 7) << 4);
      a_hi[ks] = *(const short8*)(smem + byte);
    }
  }
  __syncthreads();  // z reads done; region becomes chunk dbuf

  // ---- prologue: stage chunk 0 (64 codes bf16 = 8KB) into parity 0 ----
  const char* cbh = ws + WS_CBHI_B;
  {
    #pragma unroll
    for (int pas = 0; pas < 2; ++pas) {
      int o = t + pas * 256;           // o in [0,512): 16B units
      int dst = (o * 16) ^ (((o >> 3) & 7) << 4);
      *(f32x4*)(smem + dst) = *(const f32x4*)(cbh + o * 16);
    }
  }
  __syncthreads();

  // per-lane state: 4 rows (row = wv*16 + lg*4 + j).
  // b1/b2 PACKED (validated R10/R11/R13/R17): low 10 mantissa bits cleared,
  // code OR'd in; exact fp32 rescore of BOTH candidates arbitrates.
  float m[4], S1[4], S2[4], b1[4], b2[4];
  #pragma unroll
  for (int j = 0; j < 4; ++j) {
    m[j] = -1e30f; S1[j] = 0.f; S2[j] = 0.f; b1[j] = -1e30f; b2[j] = -1e30f;
  }

  const float* cnf = (const float*)(ws + WS_CNORM_B);

  for (int ch = 0; ch < 16; ++ch) {
    char* cur = smem + (ch & 1) * 8192;
    char* nxt = smem + ((ch + 1) & 1) * 8192;
    f32x4 rh0, rh1;
    const bool pf = ch < 15;
    if (pf) {  // prefetch next chunk into regs; latency hides under compute
      const char* sh = cbh + (ch + 1) * 8192 + t * 16;
      rh0 = *(const f32x4*)sh;
      rh1 = *(const f32x4*)(sh + 4096);
    }
    float cn2[4];
    #pragma unroll
    for (int ct = 0; ct < 4; ++ct) cn2[ct] = nw * cnf[ch * 64 + ct * 16 + lr];

    f32x4 acc[4];
    #pragma unroll
    for (int ct = 0; ct < 4; ++ct) {
      f32x4 a = {};
      #pragma unroll
      for (int ks = 0; ks < 2; ++ks) {
        int cr = ct * 16 + lr;
        int byte = (cr * 128 + ks * 64 + lg * 16) ^ ((cr & 7) << 4);
        short8 bh = *(const short8*)(cur + byte);
        a = __builtin_amdgcn_mfma_f32_16x16x32_bf16(a_hi[ks], bh, a, 0, 0, 0);
      }
      acc[ct] = a;
    }

    // epilogue: online-max rescale + packed fmax top-2 (VERBATIM R17)
    #pragma unroll
    for (int j = 0; j < 4; ++j) {
      float lv[4];
      #pragma unroll
      for (int ct = 0; ct < 4; ++ct) lv[ct] = fmaf(acc[ct][j], w2, cn2[ct]);
      float lm = fmaxf(fmaxf(lv[0], lv[1]), fmaxf(lv[2], lv[3]));
      float mn = fmaxf(m[j], lm);
      float sc = __expf(m[j] - mn);
      S1[j] *= sc; S2[j] *= sc; m[j] = mn;
      #pragma unroll
      for (int ct = 0; ct < 4; ++ct) {
        float x = lv[ct];
        unsigned ku = (unsigned)(ch * 64 + ct * 16 + lr);
        unsigned xb = (__builtin_bit_cast(unsigned, x) & ~1023u) | ku;
        float xp = __builtin_bit_cast(float, xb);
        float tm = fminf(b1[j], xp);
        b1[j] = fmaxf(b1[j], xp);
        b2[j] = fmaxf(b2[j], tm);
        float e = __expf(x - mn);
        S1[j] += e;
        S2[j] = fmaf(x, e, S2[j]);   // S2 = sum x * e^{x-m}
      }
    }

    if (pf) {
      #pragma unroll
      for (int pas = 0; pas < 2; ++pas) {
        int o = t + pas * 256;
        int dst = (o * 16) ^ (((o >> 3) & 7) << 4);
        *(f32x4*)(nxt + dst) = pas ? rh1 : rh0;
      }
    }
    __syncthreads();
  }

  // ---- merge the 16 code-columns within each wave (VERBATIM R17) ----
  #pragma unroll
  for (int st = 1; st < 16; st <<= 1) {
    #pragma unroll
    for (int j = 0; j < 4; ++j) {
      float om = __shfl_xor(m[j], st);
      float o1 = __shfl_xor(S1[j], st);
      float o2 = __shfl_xor(S2[j], st);
      float ov1 = __shfl_xor(b1[j], st);
      float ov2 = __shfl_xor(b2[j], st);
      float mn = fmaxf(m[j], om);
      float sa = __expf(m[j] - mn), sb = __expf(om - mn);
      S1[j] = sa * S1[j] + sb * o1;
      S2[j] = sa * S2[j] + sb * o2;
      m[j] = mn;
      float nb1 = fmaxf(b1[j], ov1);
      float nb2 = fmaxf(fminf(b1[j], ov1), fmaxf(b2[j], ov2));
      b1[j] = nb1; b2[j] = nb2;
    }
  }

  // ---- state write: 64 rows x 20 B scalar stores (VERBATIM R17) ----
  float* stw = (float*)(smem + ST_OFF);
  if (lr == 0) {
    #pragma unroll
    for (int j = 0; j < 4; ++j) {
      int r = wv * 16 + lg * 4 + j;
      float* p = stw + r * 5;
      p[0] = m[j]; p[1] = S1[j]; p[2] = S2[j]; p[3] = b1[j]; p[4] = b2[j];
    }
  }
  __syncthreads();

  // ---- per-row tail (wave 0): entropy + exact fp32 top-2 rescore ----
  int* fidx = (int*)(smem + FIDX_OFF);
  float rowent = 0.f, d2min = 0.f;
  if (t < 64) {
    const float* p = stw + t * 5;
    float mn = p[0], s1 = p[1], s2 = p[2];
    int ka = (int)(__builtin_bit_cast(unsigned, p[3]) & 1023u);
    int kb = (int)(__builtin_bit_cast(unsigned, p[4]) & 1023u);
    rowent = (s2 - mn * s1) / s1 - __logf(s1);
    const float* zp = z + bb * 65536 + p0 + t;
    const float* c1p = cb + ka * 64;
    const float* c2p = cb + kb * 64;
    float zn = 0.f, d1 = 0.f, d2 = 0.f;
    #pragma unroll 4
    for (int d4 = 0; d4 < 16; ++d4) {
      f32x4 ca = *(const f32x4*)(c1p + d4 * 4);
      f32x4 cc = *(const f32x4*)(c2p + d4 * 4);
      #pragma unroll
      for (int e = 0; e < 4; ++e) {
        float v = zp[(d4 * 4 + e) * 1024];
        zn = fmaf(v, v, zn);
        d1 = fmaf(v, ca[e], d1);
        d2 = fmaf(v, cc[e], d2);
      }
    }
    float da = zn + cnf[ka] - 2.f * d1;
    float db = zn + cnf[kb] - 2.f * d2;
    int kwin; float dwin;
    if (da < db || (da == db && ka < kb)) { kwin = ka; dwin = da; }
    else { kwin = kb; dwin = db; }
    fidx[t] = kwin;
    d2min = dwin;
    atomicAdd((unsigned*)(ws + WS_COUNTS_B) + kwin, 1u);
  }
  #pragma unroll
  for (int o = 32; o > 0; o >>= 1) {
    rowent += __shfl_down(rowent, o);
    d2min += __shfl_down(d2min, o);
  }
  if (t == 0) {
    float* wsf = (float*)ws;
    int slot = b & 63;
    atomicAdd(&wsf[slot * 2], rowent);
    atomicAdd(&wsf[slot * 2 + 1], d2min);
  }
  __syncthreads();

  // ---- gather chosen codes via LDS (fp32), write transposed coalesced ----
  float* zl = (float*)smem;  // dbuf region dead now (4096 words used)
  for (int i = 0; i < 16; ++i) {
    int idx = t + i * 256;
    int r = idx >> 6, d = idx & 63;
    zl[qw(r, d)] = cb[fidx[r] * 64 + d];
  }
  __syncthreads();
  float* outz = out + bb * 65536 + p0;
  #pragma unroll
  for (int i = 0; i < 4; ++i) {
    int q = t + i * 256;
    int d = q >> 4, rq = q & 15, r = rq << 2;
    f32x4 v;
    v.x = zl[qw(r + 0, d)];
    v.y = zl[qw(r + 1, d)];
    v.z = zl[qw(r + 2, d)];
    v.w = zl[qw(r + 3, d)];
    *(f32x4*)&outz[d * 1024 + r] = v;
  }
}

__global__ __launch_bounds__(1024) void vq_finalize(const float* __restrict__ var_q,
                                                    char* __restrict__ ws,
                                                    float* __restrict__ out) {
  __shared__ float red[48];
  int t = threadIdx.x;
  const unsigned* counts = (const unsigned*)(ws + WS_COUNTS_B);
  const float* wsf = (const float*)ws;
  float avg = (float)counts[t] * (1.0f / 65536.0f);
  float term = avg * __logf(avg + 1e-7f);
  float pd = 0.f, pc = 0.f;
  if (t < 64) { pd = wsf[2 * t]; pc = wsf[2 * t + 1]; }
  #pragma unroll
  for (int o = 32; o > 0; o >>= 1) {
    term += __shfl_down(term, o);
    pd += __shfl_down(pd, o);
    pc += __shfl_down(pc, o);
  }
  int wv = t >> 6, lane = t & 63;
  if (lane == 0) { red[wv * 3] = term; red[wv * 3 + 1] = pd; red[wv * 3 + 2] = pc; }
  __syncthreads();
  if (t == 0) {
    float ts = 0.f, ps = 0.f, cs = 0.f;
    #pragma unroll
    for (int i = 0; i < 16; ++i) {
      ts += red[i * 3]; ps += red[i * 3 + 1]; cs += red[i * 3 + 2];
    }
    float w = 0.5f / fmaxf(var_q[0], 1e-10f);
    out[4194304] = ps / 64.f + w * cs / 64.f;
    out[4194305] = __expf(-ts);
  }
}

extern "C" void kernel_launch(void* const* d_in, const int* in_sizes, int n_in,
                              void* d_out, int out_size, void* d_ws, size_t ws_size,
                              hipStream_t stream) {
  const float* z = (const float*)d_in[0];
  const float* vq = (const float*)d_in[1];
  const float* cb = (const float*)d_in[2];
  float* out = (float*)d_out;
  char* ws = (char*)d_ws;

  vq_prep<<<256, 256, 0, stream>>>(cb, ws);
  vq_main<<<1024, 256, 0, stream>>>(z, cb, vq, ws, out);
  vq_finalize<<<1, 1024, 0, stream>>>(vq, ws, out);
}